// Round 3
// baseline (2968.451 us; speedup 1.0000x reference)
//
#include <hip/hip_runtime.h>
#include <hip/hip_bf16.h>
#include <math.h>

#define NL 30
#define NM 80
#define Bx 8
#define Tx 8192

typedef short short8 __attribute__((ext_vector_type(8)));
typedef float f32x4 __attribute__((ext_vector_type(4)));
typedef unsigned int u32x2 __attribute__((ext_vector_type(2)));
typedef unsigned int u32x4 __attribute__((ext_vector_type(4)));

__device__ __forceinline__ float bf2f(unsigned short u) {
    union { unsigned int u; float f; } v; v.u = ((unsigned int)u) << 16; return v.f;
}
__device__ __forceinline__ unsigned short f2bf(float f) {
    union { float f; unsigned int u; } v; v.f = f;
    unsigned int r = v.u + 0x7FFFu + ((v.u >> 16) & 1u);
    return (unsigned short)(r >> 16);
}

#if defined(__has_builtin)
#if __has_builtin(__builtin_amdgcn_global_load_lds)
#define HAS_GLL 1
#endif
#endif

__device__ __forceinline__ void gll16(const void* g, void* l) {
#ifdef HAS_GLL
    __builtin_amdgcn_global_load_lds(
        (const __attribute__((address_space(1))) void*)g,
        (__attribute__((address_space(3))) void*)l, 16, 0, 0);
#else
    int lane = threadIdx.x & 63;
    *(u32x4*)((char*)l + lane * 16) = *(const u32x4*)((const char*)g + lane * 16);
#endif
}

// per-batch grid barrier: 64 blocks arrive; monotonic counter (reset per launch
// by captured hipMemsetAsync). Producer/consumer all on one XCD (batch<->XCD swizzle).
__device__ __forceinline__ void gbar(unsigned int* c, unsigned int target) {
    __syncthreads();                 // drains vmcnt: all our stores are in L2 (write-through)
    if (threadIdx.x == 0) {
        __threadfence();             // release
        atomicAdd(c, 1u);
        int guard = 0;
        while (__hip_atomic_load(c, __ATOMIC_RELAXED, __HIP_MEMORY_SCOPE_AGENT) < target) {
            __builtin_amdgcn_s_sleep(2);
            if (++guard > (1 << 22)) break;   // anti-hang insurance; never triggers if co-resident
        }
    }
    __syncthreads();
    __threadfence();                 // acquire: invalidate L1 so fresh h is visible
}

// ---------------- time-embedding MLP: 8 blocks (one per batch) ----------------
__global__ void te_kernel(const int* __restrict__ tin,
                          const float* __restrict__ w1, const float* __restrict__ b1,
                          const float* __restrict__ w2, const float* __restrict__ b2,
                          float* __restrict__ te_out) {
    __shared__ float emb[128];
    __shared__ float h1s[512];
    __shared__ float red[512];
    int b = blockIdx.x, tid = threadIdx.x;
    if (tid < 64) {
        float fr = expf(-(float)tid * (logf(10000.f) / 63.f));
        float ang = (float)tin[b] * fr;
        emb[tid] = sinf(ang);
        emb[tid + 64] = cosf(ang);
    }
    __syncthreads();
    float a = b1[tid];
    const float* wr = w1 + tid * 128;
    for (int k = 0; k < 128; ++k) a = fmaf(emb[k], wr[k], a);
    float sp = (a > 15.f) ? a : log1pf(expf(a));
    h1s[tid] = a * tanhf(sp);
    __syncthreads();
    int o = tid & 127, q = tid >> 7;
    float p = 0.f;
    const float* wr2 = w2 + o * 512 + q * 128;
    const float* hq = h1s + q * 128;
    for (int k = 0; k < 128; ++k) p = fmaf(hq[k], wr2[k], p);
    red[tid] = p;
    __syncthreads();
    if (q == 0)
        te_out[b * 128 + o] = b2[o] + red[o] + red[o + 128] + red[o + 256] + red[o + 384];
}

// ---------------- per-layer (b,ch) bias: dconv_b + sign(tp) + sign(cp) ----------------
__global__ void gbias_kernel(const float* __restrict__ te,
                             const float* __restrict__ cemb,
                             const float* __restrict__ tpw, const float* __restrict__ tpb,
                             const float* __restrict__ cpw, const float* __restrict__ cpb,
                             const float* __restrict__ dcb,
                             float* __restrict__ gbias) {
    int l = blockIdx.x >> 3;
    int b = blockIdx.x & 7;
    int ch = threadIdx.x;
    float tp = tpb[l * 128 + ch];
    const float* wr = tpw + (size_t)(l * 128 + ch) * 128;
    const float* tb = te + b * 128;
    for (int k = 0; k < 128; ++k) tp = fmaf(tb[k], wr[k], tp);
    float s1 = tp / fmaxf(fabsf(tp), 1e-12f);
    float cp = cpb[l * 128 + ch];
    const float* wcp = cpw + (size_t)(l * 128 + ch) * 256;
    const float* cb = cemb + b * 256;
    for (int k = 0; k < 256; ++k) cp = fmaf(cb[k], wcp[k], cp);
    float s2 = cp / fmaxf(fabsf(cp), 1e-12f);
    gbias[(l * 8 + b) * 128 + ch] = dcb[l * 128 + ch] + s1 + s2;
}

// ---------------- weight prep (pre-swizzled conv weights; bf16 casts) ----------------
__global__ void prep_kernel(const float* __restrict__ dconv_w, const float* __restrict__ rs_w,
                            const float* __restrict__ skip_w, const float* __restrict__ out_w,
                            unsigned short* __restrict__ wc2, unsigned short* __restrict__ wr2,
                            unsigned short* __restrict__ skw16, unsigned short* __restrict__ oww16) {
    int idx = blockIdx.x * 256 + threadIdx.x;
    const int totC = NL * 24576;
    const int totR = NL * 128 * 64;
    if (idx < totC) {
        int l = idx / 24576;
        int r = idx - l * 24576;
        int c = r >> 3;
        int e = r & 7;
        int row = c >> 3;
        int p = c & 7;
        int col16 = p ^ (row & 7);
        int ic = col16 * 8 + e;
        int tap = row >> 7;
        int oc = row & 127;
        wc2[idx] = f2bf(dconv_w[((size_t)(l * 128 + oc) * 64 + ic) * 3 + tap]);
    } else if (idx < totC + totR) {
        int j = idx - totC;
        wr2[j] = f2bf(rs_w[j]);
    } else if (idx < totC + totR + 4096) {
        int j = idx - totC - totR;
        skw16[j] = f2bf(skip_w[j] * 0.18257418583505536f);
    } else if (idx < totC + totR + 4096 + 5120) {
        int j = idx - totC - totR - 4096;
        oww16[j] = f2bf(out_w[j]);
    }
}

// ---------------- input conv 80->64 + transpose to (B,T,64) bf16 ----------------
__global__ void in_conv_kernel(const float* __restrict__ x, const float* __restrict__ w,
                               const float* __restrict__ bias, unsigned short* __restrict__ h0) {
    __shared__ float wT[NM][64];
    int tid = threadIdx.x;
    for (int i = tid; i < NM * 64; i += 256) {
        int m = i >> 6, c = i & 63;
        wT[m][c] = w[c * NM + m];
    }
    __syncthreads();
    int b = blockIdx.y;
    int t = blockIdx.x * 128 + (tid >> 1);
    int ch0 = (tid & 1) * 32;
    const float* xp = x + (size_t)b * NM * Tx + t;
    float acc[32];
    #pragma unroll
    for (int c = 0; c < 32; ++c) acc[c] = bias[ch0 + c];
    for (int m = 0; m < NM; ++m) {
        float xv = xp[(size_t)m * Tx];
        #pragma unroll
        for (int c = 0; c < 32; ++c) acc[c] = fmaf(xv, wT[m][ch0 + c], acc[c]);
    }
    unsigned short* hp = h0 + ((size_t)b * Tx + t) * 64 + ch0;
    #pragma unroll
    for (int c = 0; c < 32; c += 2) {
        unsigned int p = (unsigned int)f2bf(acc[c]) | ((unsigned int)f2bf(acc[c + 1]) << 16);
        *(unsigned int*)(hp + c) = p;
    }
}

// ---------------- persistent all-layer kernel + fused output tail ----------------
// 512 blocks x 512 thr (2/CU), 8 waves = 2 pos-grp x 4 och-grp; block = 128 positions.
// skip accumulator lives in registers across all 30 layers. Per-batch grid barrier
// between layers (batch k -> XCD k, so h + barrier traffic is XCD-local).
__launch_bounds__(512, 4)
__global__ void net_kernel(const unsigned short* __restrict__ hA,
                           unsigned short* __restrict__ hB,
                           const unsigned short* __restrict__ wc2a,
                           const unsigned short* __restrict__ wr2a,
                           const float* __restrict__ gba,
                           const float* __restrict__ rsba,
                           const unsigned short* __restrict__ skw,
                           const float* __restrict__ skb,
                           const unsigned short* __restrict__ oww,
                           const float* __restrict__ obias,
                           unsigned int* __restrict__ ctr,
                           float* __restrict__ y) {
    __shared__ __align__(16) unsigned char ldsA[49152];   // conv weights (swizzled)
    __shared__ __align__(16) unsigned char ldsO[16384];   // 128 pos x 128B exchange

    int tid = threadIdx.x;
    int wid = tid >> 6, lane = tid & 63, lr = lane & 15, lq = lane >> 4;
    int bid = blockIdx.x;
    int b = bid & 7;                 // batch == XCD
    int t_blk = (bid >> 3) * 128;
    int grp = wid >> 2, g = wid & 3;
    int t_grp = t_blk + grp * 64;
    const float inv_s2 = 0.70710678118654752f;

    f32x4 skacc[4];
    #pragma unroll
    for (int nf = 0; nf < 4; ++nf) { skacc[nf][0] = 0.f; skacc[nf][1] = 0.f; skacc[nf][2] = 0.f; skacc[nf][3] = 0.f; }

    const unsigned short* hin = hA;
    unsigned short* hout = hB;

    #pragma unroll 1
    for (int i = 0; i < NL; ++i) {
        // stage conv weights for this layer (content pre-swizzled -> linear copy)
        const unsigned short* wc2 = wc2a + (size_t)i * 24576;
        #pragma unroll
        for (int j = 0; j < 6; ++j) {
            int cbase = j * 512 + wid * 64;
            gll16(wc2 + (size_t)(cbase + lane) * 8, ldsA + cbase * 16);
        }

        f32x4 acc0[4], acc1[4];
        {
            f32x4 bg = *(const f32x4*)(gba + (size_t)(i * 8 + b) * 128 + g * 16 + lq * 4);
            f32x4 bfv = *(const f32x4*)(gba + (size_t)(i * 8 + b) * 128 + 64 + g * 16 + lq * 4);
            #pragma unroll
            for (int nf = 0; nf < 4; ++nf) { acc0[nf] = bg; acc1[nf] = bfv; }
        }
        __syncthreads();   // weights staged (vmcnt drained)

        int dil = 1 << (i % 10);
        const unsigned short* hb = hin + (size_t)b * Tx * 64;
        #pragma unroll
        for (int tap = 0; tap < 3; ++tap) {
            int toff = (tap - 1) * dil;
            short8 bv[4][2];
            #pragma unroll
            for (int nf = 0; nf < 4; ++nf) {
                int t = t_grp + nf * 16 + lr + toff;
                bool v = ((unsigned)t < (unsigned)Tx);
                #pragma unroll
                for (int kc = 0; kc < 2; ++kc) {
                    short8 z = {0, 0, 0, 0, 0, 0, 0, 0};
                    if (v) z = *(const short8*)(hb + t * 64 + kc * 32 + lq * 8);
                    bv[nf][kc] = z;
                }
            }
            #pragma unroll
            for (int kc = 0; kc < 2; ++kc) {
                int rowg = tap * 128 + g * 16 + lr;
                int swz = (kc * 64 + lq * 16) ^ ((lr & 7) << 4);
                short8 aG = *(const short8*)(ldsA + rowg * 128 + swz);
                short8 aF = *(const short8*)(ldsA + (rowg + 64) * 128 + swz);
                #pragma unroll
                for (int nf = 0; nf < 4; ++nf) {
                    acc0[nf] = __builtin_amdgcn_mfma_f32_16x16x32_bf16(aG, bv[nf][kc], acc0[nf], 0, 0, 0);
                    acc1[nf] = __builtin_amdgcn_mfma_f32_16x16x32_bf16(aF, bv[nf][kc], acc1[nf], 0, 0, 0);
                }
            }
        }

        // gating -> ldsO (bf16, swizzled)
        #pragma unroll
        for (int nf = 0; nf < 4; ++nf) {
            int p = grp * 64 + nf * 16 + lr;
            unsigned short ob[4];
            #pragma unroll
            for (int r = 0; r < 4; ++r) {
                float gg = acc0[nf][r];
                float ff = acc1[nf][r];
                ff = fminf(ff, 15.f);
                gg = fminf(gg, 30.f);
                float ea = __builtin_amdgcn_exp2f(ff * 2.8853900817779268f);
                float eb = __builtin_amdgcn_exp2f(gg * 1.4426950408889634f);
                float num = (ea - 1.f) * eb;
                float den = (ea + 1.f) * (1.f + eb);
                ob[r] = f2bf(num * __builtin_amdgcn_rcpf(den));
            }
            u32x2 pk;
            pk[0] = (unsigned int)ob[0] | ((unsigned int)ob[1] << 16);
            pk[1] = (unsigned int)ob[2] | ((unsigned int)ob[3] << 16);
            *(u32x2*)(ldsO + p * 128 + ((g * 32 + lq * 8) ^ ((p & 7) << 4))) = pk;
        }

        // rs A-frags for this layer
        const unsigned short* wr2 = wr2a + (size_t)i * 8192;
        short8 rA[2][2];
        #pragma unroll
        for (int m = 0; m < 2; ++m) {
            int och = (m ? 64 : 0) + g * 16 + lr;
            #pragma unroll
            for (int kc = 0; kc < 2; ++kc)
                rA[m][kc] = *(const short8*)(wr2 + och * 64 + kc * 32 + lq * 8);
        }
        __syncthreads();   // out exchange ready

        // rs accumulators: res from bias; skip accumulates in registers
        const float* rsb = rsba + (size_t)i * 128;
        f32x4 racc0[4], racc1[4];
        {
            f32x4 r0 = *(const f32x4*)(rsb + g * 16 + lq * 4);
            f32x4 r1 = *(const f32x4*)(rsb + 64 + g * 16 + lq * 4);
            #pragma unroll
            for (int nf = 0; nf < 4; ++nf) { racc0[nf] = r0; racc1[nf] = skacc[nf] + r1; }
        }

        // prefetch h_old for epilogue
        u32x2 hold[4];
        #pragma unroll
        for (int nf = 0; nf < 4; ++nf) {
            int t = t_grp + nf * 16 + lr;
            hold[nf] = *(const u32x2*)(hin + ((size_t)b * Tx + t) * 64 + g * 16 + lq * 4);
        }

        #pragma unroll
        for (int kc = 0; kc < 2; ++kc) {
            #pragma unroll
            for (int nf = 0; nf < 4; ++nf) {
                int p = grp * 64 + nf * 16 + lr;
                short8 ov = *(const short8*)(ldsO + p * 128 + ((kc * 64 + lq * 16) ^ ((p & 7) << 4)));
                racc0[nf] = __builtin_amdgcn_mfma_f32_16x16x32_bf16(rA[0][kc], ov, racc0[nf], 0, 0, 0);
                racc1[nf] = __builtin_amdgcn_mfma_f32_16x16x32_bf16(rA[1][kc], ov, racc1[nf], 0, 0, 0);
            }
        }

        // epilogue: h_out = h_in + res/sqrt(2); skip stays in registers
        #pragma unroll
        for (int nf = 0; nf < 4; ++nf) {
            int t = t_grp + nf * 16 + lr;
            unsigned short* hp = (unsigned short*)&hold[nf];
            unsigned short hnew[4];
            #pragma unroll
            for (int r = 0; r < 4; ++r)
                hnew[r] = f2bf(bf2f(hp[r]) + racc0[nf][r] * inv_s2);
            u32x2 hw;
            hw[0] = (unsigned int)hnew[0] | ((unsigned int)hnew[1] << 16);
            hw[1] = (unsigned int)hnew[2] | ((unsigned int)hnew[3] << 16);
            *(u32x2*)(hout + ((size_t)b * Tx + t) * 64 + g * 16 + lq * 4) = hw;
            skacc[nf] = racc1[nf];
        }

        const unsigned short* tmp = hin;
        hin = hout;
        hout = (unsigned short*)tmp;

        if (i < NL - 1) gbar(ctr + b * 64, 64u * (unsigned)(i + 1));
    }

    // ---------------- fused output tail: skip(regs) -> skip_conv+relu -> out_conv ----------------
    __syncthreads();   // everyone done with ldsO reads of layer 29
    #pragma unroll
    for (int nf = 0; nf < 4; ++nf) {
        int p = grp * 64 + nf * 16 + lr;
        f32x4 s = skacc[nf];
        u32x2 pk;
        pk[0] = (unsigned int)f2bf(s[0]) | ((unsigned int)f2bf(s[1]) << 16);
        pk[1] = (unsigned int)f2bf(s[2]) | ((unsigned int)f2bf(s[3]) << 16);
        *(u32x2*)(ldsO + p * 128 + ((g * 32 + lq * 8) ^ ((p & 7) << 4))) = pk;
    }
    __syncthreads();

    // stage 1: y1[och 16g..16g+16) for this wave's 64 positions
    f32x4 yacc[4];
    {
        f32x4 bb = *(const f32x4*)(skb + g * 16 + lq * 4);
        #pragma unroll
        for (int nf = 0; nf < 4; ++nf) yacc[nf] = bb;
    }
    #pragma unroll
    for (int kc = 0; kc < 2; ++kc) {
        short8 A1 = *(const short8*)(skw + (g * 16 + lr) * 64 + kc * 32 + lq * 8);
        #pragma unroll
        for (int nf = 0; nf < 4; ++nf) {
            int p = grp * 64 + nf * 16 + lr;
            short8 Bv = *(const short8*)(ldsO + p * 128 + ((kc * 64 + lq * 16) ^ ((p & 7) << 4)));
            yacc[nf] = __builtin_amdgcn_mfma_f32_16x16x32_bf16(A1, Bv, yacc[nf], 0, 0, 0);
        }
    }
    // relu -> bf16 -> ldsA (weights done, reuse as y1 exchange)
    #pragma unroll
    for (int nf = 0; nf < 4; ++nf) {
        int p = grp * 64 + nf * 16 + lr;
        unsigned short ob[4];
        #pragma unroll
        for (int r = 0; r < 4; ++r) ob[r] = f2bf(fmaxf(yacc[nf][r], 0.f));
        u32x2 pk;
        pk[0] = (unsigned int)ob[0] | ((unsigned int)ob[1] << 16);
        pk[1] = (unsigned int)ob[2] | ((unsigned int)ob[3] << 16);
        *(u32x2*)(ldsA + p * 128 + ((g * 32 + lq * 8) ^ ((p & 7) << 4))) = pk;
    }
    __syncthreads();

    // stage 2: out channels; g owns mf=g (and g==3 also mf=4)
    int nmf = (g == 3) ? 2 : 1;
    for (int mi = 0; mi < nmf; ++mi) {
        int mf = (mi == 0) ? g : 4;
        f32x4 oacc[4];
        {
            f32x4 bb = *(const f32x4*)(obias + mf * 16 + lq * 4);
            #pragma unroll
            for (int nf = 0; nf < 4; ++nf) oacc[nf] = bb;
        }
        #pragma unroll
        for (int kc = 0; kc < 2; ++kc) {
            short8 A2 = *(const short8*)(oww + (mf * 16 + lr) * 64 + kc * 32 + lq * 8);
            #pragma unroll
            for (int nf = 0; nf < 4; ++nf) {
                int p = grp * 64 + nf * 16 + lr;
                short8 B2 = *(const short8*)(ldsA + p * 128 + ((kc * 64 + lq * 16) ^ ((p & 7) << 4)));
                oacc[nf] = __builtin_amdgcn_mfma_f32_16x16x32_bf16(A2, B2, oacc[nf], 0, 0, 0);
            }
        }
        #pragma unroll
        for (int nf = 0; nf < 4; ++nf) {
            int t = t_grp + nf * 16 + lr;
            #pragma unroll
            for (int r = 0; r < 4; ++r) {
                int m = mf * 16 + lq * 4 + r;
                y[((size_t)b * NM + m) * Tx + t] = oacc[nf][r];
            }
        }
    }
}

extern "C" void kernel_launch(void* const* d_in, const int* in_sizes, int n_in,
                              void* d_out, int out_size, void* d_ws, size_t ws_size,
                              hipStream_t stream) {
    const float* x       = (const float*)d_in[0];
    const int*   tin     = (const int*)d_in[1];
    const float* c_emb   = (const float*)d_in[2];
    const float* in_w    = (const float*)d_in[3];
    const float* in_b    = (const float*)d_in[4];
    const float* te_w1   = (const float*)d_in[5];
    const float* te_b1   = (const float*)d_in[6];
    const float* te_w2   = (const float*)d_in[7];
    const float* te_b2   = (const float*)d_in[8];
    const float* dconv_w = (const float*)d_in[9];
    const float* dconv_b = (const float*)d_in[10];
    const float* tproj_w = (const float*)d_in[11];
    const float* tproj_b = (const float*)d_in[12];
    const float* cproj_w = (const float*)d_in[13];
    const float* cproj_b = (const float*)d_in[14];
    const float* rs_w    = (const float*)d_in[15];
    const float* rs_b    = (const float*)d_in[16];
    const float* skip_w  = (const float*)d_in[17];
    const float* skip_b  = (const float*)d_in[18];
    const float* out_w   = (const float*)d_in[19];
    const float* out_b   = (const float*)d_in[20];

    char* ws = (char*)d_ws;
    float* te_buf         = (float*)(ws + 0);                 // 4KB
    float* gbias          = (float*)(ws + 4096);              // 120KB -> 126976
    unsigned short* skw16 = (unsigned short*)(ws + 126976);   // 8KB  -> 135168
    unsigned short* oww16 = (unsigned short*)(ws + 135168);   // 10KB -> 145408
    unsigned short* wc2   = (unsigned short*)(ws + 145408);   // 1.40625MB -> 1619968
    unsigned short* wr2   = (unsigned short*)(ws + 1619968);  // 480KB -> 2111488
    unsigned short* h0    = (unsigned short*)(ws + 2111488);  // 8MB -> 10500096
    unsigned short* h1    = (unsigned short*)(ws + 10500096); // 8MB -> 18888704
    unsigned int* ctr     = (unsigned int*)(ws + 18888704);   // 2KB (8 counters, 256B apart)

    te_kernel<<<8, 512, 0, stream>>>(tin, te_w1, te_b1, te_w2, te_b2, te_buf);
    gbias_kernel<<<240, 128, 0, stream>>>(te_buf, c_emb, tproj_w, tproj_b,
                                          cproj_w, cproj_b, dconv_b, gbias);
    prep_kernel<<<3876, 256, 0, stream>>>(dconv_w, rs_w, skip_w, out_w,
                                          wc2, wr2, skw16, oww16);
    in_conv_kernel<<<dim3(64, 8), 256, 0, stream>>>(x, in_w, in_b, h0);
    hipMemsetAsync(ctr, 0, 2048, stream);
    net_kernel<<<512, 512, 0, stream>>>(h0, h1, wc2, wr2, gbias, rs_b,
                                        skw16, skip_b, oww16, out_b, ctr,
                                        (float*)d_out);
}

// Round 4
// 590.093 us; speedup vs baseline: 5.0305x; 5.0305x over previous
//
#include <hip/hip_runtime.h>
#include <hip/hip_bf16.h>
#include <math.h>

#define NL 30
#define NM 80
#define Bx 8
#define Tx 8192

typedef short short8 __attribute__((ext_vector_type(8)));
typedef float f32x4 __attribute__((ext_vector_type(4)));
typedef unsigned int u32x2 __attribute__((ext_vector_type(2)));
typedef unsigned int u32x4 __attribute__((ext_vector_type(4)));

__device__ __forceinline__ float bf2f(unsigned short u) {
    union { unsigned int u; float f; } v; v.u = ((unsigned int)u) << 16; return v.f;
}
__device__ __forceinline__ unsigned short f2bf(float f) {
    union { float f; unsigned int u; } v; v.f = f;
    unsigned int r = v.u + 0x7FFFu + ((v.u >> 16) & 1u);
    return (unsigned short)(r >> 16);
}

#if defined(__has_builtin)
#if __has_builtin(__builtin_amdgcn_global_load_lds)
#define HAS_GLL 1
#endif
#endif

__device__ __forceinline__ void gll16(const void* g, void* l) {
#ifdef HAS_GLL
    __builtin_amdgcn_global_load_lds(
        (const __attribute__((address_space(1))) void*)g,
        (__attribute__((address_space(3))) void*)l, 16, 0, 0);
#else
    int lane = threadIdx.x & 63;
    *(u32x4*)((char*)l + lane * 16) = *(const u32x4*)((const char*)g + lane * 16);
#endif
}

// ---------------- time-embedding MLP: 8 blocks (one per batch) ----------------
__global__ void te_kernel(const int* __restrict__ tin,
                          const float* __restrict__ w1, const float* __restrict__ b1,
                          const float* __restrict__ w2, const float* __restrict__ b2,
                          float* __restrict__ te_out) {
    __shared__ float emb[128];
    __shared__ float h1s[512];
    __shared__ float red[512];
    int b = blockIdx.x, tid = threadIdx.x;
    if (tid < 64) {
        float fr = expf(-(float)tid * (logf(10000.f) / 63.f));
        float ang = (float)tin[b] * fr;
        emb[tid] = sinf(ang);
        emb[tid + 64] = cosf(ang);
    }
    __syncthreads();
    float a = b1[tid];
    const float* wr = w1 + tid * 128;
    for (int k = 0; k < 128; ++k) a = fmaf(emb[k], wr[k], a);
    float sp = (a > 15.f) ? a : log1pf(expf(a));
    h1s[tid] = a * tanhf(sp);
    __syncthreads();
    int o = tid & 127, q = tid >> 7;
    float p = 0.f;
    const float* wr2 = w2 + o * 512 + q * 128;
    const float* hq = h1s + q * 128;
    for (int k = 0; k < 128; ++k) p = fmaf(hq[k], wr2[k], p);
    red[tid] = p;
    __syncthreads();
    if (q == 0)
        te_out[b * 128 + o] = b2[o] + red[o] + red[o + 128] + red[o + 256] + red[o + 384];
}

// ---------------- per-layer (b,ch) bias: dconv_b + sign(tp) + sign(cp) ----------------
__global__ void gbias_kernel(const float* __restrict__ te,
                             const float* __restrict__ cemb,
                             const float* __restrict__ tpw, const float* __restrict__ tpb,
                             const float* __restrict__ cpw, const float* __restrict__ cpb,
                             const float* __restrict__ dcb,
                             float* __restrict__ gbias) {
    int l = blockIdx.x >> 3;
    int b = blockIdx.x & 7;
    int ch = threadIdx.x;
    float tp = tpb[l * 128 + ch];
    const float* wr = tpw + (size_t)(l * 128 + ch) * 128;
    const float* tb = te + b * 128;
    for (int k = 0; k < 128; ++k) tp = fmaf(tb[k], wr[k], tp);
    float s1 = tp / fmaxf(fabsf(tp), 1e-12f);
    float cp = cpb[l * 128 + ch];
    const float* wcp = cpw + (size_t)(l * 128 + ch) * 256;
    const float* cb = cemb + b * 256;
    for (int k = 0; k < 256; ++k) cp = fmaf(cb[k], wcp[k], cp);
    float s2 = cp / fmaxf(fabsf(cp), 1e-12f);
    gbias[(l * 8 + b) * 128 + ch] = dcb[l * 128 + ch] + s1 + s2;
}

// ---------------- weight prep ----------------
// wc2 AND wr2 are stored PRE-SWIZZLED so a linear gll16 copy lands in the
// XOR-swizzled LDS layout: linear chunk c -> row=c>>3, phys slot p=c&7 holds
// logical col16 = p ^ (row&7).
__global__ void prep_kernel(const float* __restrict__ dconv_w, const float* __restrict__ rs_w,
                            const float* __restrict__ skip_w, const float* __restrict__ out_w,
                            unsigned short* __restrict__ wc2, unsigned short* __restrict__ wr2,
                            unsigned short* __restrict__ skw16, unsigned short* __restrict__ oww16) {
    int idx = blockIdx.x * 256 + threadIdx.x;
    const int totC = NL * 24576;           // 737280
    const int totR = NL * 128 * 64;        // 245760
    if (idx < totC) {
        int l = idx / 24576;
        int r = idx - l * 24576;
        int c = r >> 3;
        int e = r & 7;
        int row = c >> 3;
        int p = c & 7;
        int col16 = p ^ (row & 7);
        int ic = col16 * 8 + e;
        int tap = row >> 7;
        int oc = row & 127;
        wc2[idx] = f2bf(dconv_w[((size_t)(l * 128 + oc) * 64 + ic) * 3 + tap]);
    } else if (idx < totC + totR) {
        int j = idx - totC;
        int l = j / 8192;
        int r = j - l * 8192;
        int c = r >> 3;
        int e = r & 7;
        int row = c >> 3;
        int p = c & 7;
        int col16 = p ^ (row & 7);
        int ic = col16 * 8 + e;
        wr2[j] = f2bf(rs_w[(size_t)(l * 128 + row) * 64 + ic]);
    } else if (idx < totC + totR + 4096) {
        int j = idx - totC - totR;
        skw16[j] = f2bf(skip_w[j] * 0.18257418583505536f);
    } else if (idx < totC + totR + 4096 + 5120) {
        int j = idx - totC - totR - 4096;
        oww16[j] = f2bf(out_w[j]);
    }
}

// ---------------- input conv 80->64 + transpose to (B,T,64) bf16 ----------------
__global__ void in_conv_kernel(const float* __restrict__ x, const float* __restrict__ w,
                               const float* __restrict__ bias, unsigned short* __restrict__ h0) {
    __shared__ float wT[NM][64];
    int tid = threadIdx.x;
    for (int i = tid; i < NM * 64; i += 256) {
        int m = i >> 6, c = i & 63;
        wT[m][c] = w[c * NM + m];
    }
    __syncthreads();
    int b = blockIdx.y;
    int t = blockIdx.x * 128 + (tid >> 1);
    int ch0 = (tid & 1) * 32;
    const float* xp = x + (size_t)b * NM * Tx + t;
    float acc[32];
    #pragma unroll
    for (int c = 0; c < 32; ++c) acc[c] = bias[ch0 + c];
    for (int m = 0; m < NM; ++m) {
        float xv = xp[(size_t)m * Tx];
        #pragma unroll
        for (int c = 0; c < 32; ++c) acc[c] = fmaf(xv, wT[m][ch0 + c], acc[c]);
    }
    unsigned short* hp = h0 + ((size_t)b * Tx + t) * 64 + ch0;
    #pragma unroll
    for (int c = 0; c < 32; c += 2) {
        unsigned int p = (unsigned int)f2bf(acc[c]) | ((unsigned int)f2bf(acc[c + 1]) << 16);
        *(unsigned int*)(hp + c) = p;
    }
}

// ---------------- fused residual layer (round-1 structure, improved) ----------------
// 8 waves; each wave: M = 128 out-ch, N = 32 positions (block = 256 positions).
// Grid 256 = 1 block/CU. LDS 96KB: 48K conv W + 16K rs W + 8x4K wave-private out.
// B-fragments + bias prefetched before the staging barrier; no conv->rs barrier
// (out buffer is wave-private); epilogue operands prefetched before rs MFMAs.
__launch_bounds__(512, 2)
__global__ void layer_kernel(const unsigned short* __restrict__ h_in,
                             unsigned short* __restrict__ h_out,
                             float* __restrict__ skips,
                             const unsigned short* __restrict__ wc2,  // pre-swizzled
                             const unsigned short* __restrict__ wr2,  // pre-swizzled
                             const float* __restrict__ gbias,         // [8][128]
                             const float* __restrict__ rsb,           // [128]
                             int dil, int first) {
    __shared__ __align__(16) unsigned char lds[98304];
    unsigned char* ldsA = lds;            // 48KB
    unsigned char* ldsR = lds + 49152;    // 16KB
    unsigned char* ldsO = lds + 65536;    // 32KB

    int tid = threadIdx.x;
    int wid = tid >> 6, lane = tid & 63, lr = lane & 15, lq = lane >> 4;

    // stage weights: linear gll16 copies (content pre-swizzled)
    #pragma unroll
    for (int j = 0; j < 6; ++j) {
        int cbase = j * 512 + wid * 64;
        gll16(wc2 + (size_t)(cbase + lane) * 8, ldsA + cbase * 16);
    }
    #pragma unroll
    for (int j = 0; j < 2; ++j) {
        int cbase = j * 512 + wid * 64;
        gll16(wr2 + (size_t)(cbase + lane) * 8, ldsR + cbase * 16);
    }

    int bid = blockIdx.x;
    int wg = (bid & 7) * 32 + (bid >> 3);   // batch k -> XCD k (perf heuristic)
    int b = wg >> 5;
    int t0 = ((wg & 31) << 8) + wid * 32;

    // prefetch conv B-fragments for all 3 taps (overlaps weight staging)
    const unsigned short* hb = h_in + (size_t)b * Tx * 64;
    short8 bv[3][2][2];
    #pragma unroll
    for (int tap = 0; tap < 3; ++tap) {
        int toff = (tap - 1) * dil;
        #pragma unroll
        for (int nf = 0; nf < 2; ++nf) {
            int t = t0 + nf * 16 + lr + toff;
            bool v = ((unsigned)t < (unsigned)Tx);
            #pragma unroll
            for (int kc = 0; kc < 2; ++kc) {
                short8 z = {0, 0, 0, 0, 0, 0, 0, 0};
                if (v) z = *(const short8*)(hb + t * 64 + kc * 32 + lq * 8);
                bv[tap][nf][kc] = z;
            }
        }
    }

    // conv accumulators init with per-(b,ch) bias
    f32x4 acc[8][2];
    #pragma unroll
    for (int mf = 0; mf < 8; ++mf) {
        f32x4 bias4 = *(const f32x4*)(gbias + b * 128 + mf * 16 + lq * 4);
        acc[mf][0] = bias4;
        acc[mf][1] = bias4;
    }
    __syncthreads();   // weights staged

    #pragma unroll
    for (int tap = 0; tap < 3; ++tap) {
        #pragma unroll
        for (int kc = 0; kc < 2; ++kc) {
            #pragma unroll
            for (int mf = 0; mf < 8; ++mf) {
                int row = tap * 128 + mf * 16 + lr;
                short8 af = *(const short8*)(ldsA + row * 128 + ((kc * 64 + lq * 16) ^ ((lr & 7) << 4)));
                acc[mf][0] = __builtin_amdgcn_mfma_f32_16x16x32_bf16(af, bv[tap][0][kc], acc[mf][0], 0, 0, 0);
                acc[mf][1] = __builtin_amdgcn_mfma_f32_16x16x32_bf16(af, bv[tap][1][kc], acc[mf][1], 0, 0, 0);
            }
        }
    }

    // gating -> wave-private ldsO (no block barrier needed)
    unsigned char* myO = ldsO + wid * 4096;
    #pragma unroll
    for (int mf = 0; mf < 4; ++mf) {
        #pragma unroll
        for (int nf = 0; nf < 2; ++nf) {
            int p = nf * 16 + lr;
            unsigned short ob[4];
            #pragma unroll
            for (int r = 0; r < 4; ++r) {
                float g = acc[mf][nf][r];       // gate: ch 0..63
                float f = acc[mf + 4][nf][r];   // filt: ch 64..127
                f = fminf(f, 15.f);
                g = fminf(g, 30.f);
                float ea = __builtin_amdgcn_exp2f(f * 2.8853900817779268f);
                float eb = __builtin_amdgcn_exp2f(g * 1.4426950408889634f);
                float num = (ea - 1.f) * eb;
                float den = (ea + 1.f) * (1.f + eb);
                ob[r] = f2bf(num * __builtin_amdgcn_rcpf(den));
            }
            u32x2 pk;
            pk[0] = (unsigned int)ob[0] | ((unsigned int)ob[1] << 16);
            pk[1] = (unsigned int)ob[2] | ((unsigned int)ob[3] << 16);
            *(u32x2*)(myO + p * 128 + ((mf * 32 + lq * 8) ^ ((p & 7) << 4))) = pk;
        }
    }

    // prefetch epilogue operands (independent of rs MFMAs)
    u32x2 hold[2][4];
    f32x4 skold[2][4];
    #pragma unroll
    for (int nf = 0; nf < 2; ++nf) {
        int t = t0 + nf * 16 + lr;
        size_t base = ((size_t)b * Tx + t) * 64;
        #pragma unroll
        for (int mf = 0; mf < 4; ++mf) {
            hold[nf][mf] = *(const u32x2*)(h_in + base + mf * 16 + lq * 4);
            if (!first) skold[nf][mf] = *(const f32x4*)(skips + base + mf * 16 + lq * 4);
            else { skold[nf][mf][0] = 0.f; skold[nf][mf][1] = 0.f; skold[nf][mf][2] = 0.f; skold[nf][mf][3] = 0.f; }
        }
    }

    // rs 1x1 conv: 64 -> 128
    f32x4 racc[8][2];
    #pragma unroll
    for (int mf = 0; mf < 8; ++mf) {
        f32x4 rb4 = *(const f32x4*)(rsb + mf * 16 + lq * 4);
        racc[mf][0] = rb4;
        racc[mf][1] = rb4;
    }
    #pragma unroll
    for (int kc = 0; kc < 2; ++kc) {
        short8 ob2[2];
        #pragma unroll
        for (int nf = 0; nf < 2; ++nf) {
            int p = nf * 16 + lr;
            ob2[nf] = *(const short8*)(myO + p * 128 + ((kc * 64 + lq * 16) ^ ((p & 7) << 4)));
        }
        #pragma unroll
        for (int mf = 0; mf < 8; ++mf) {
            int row = mf * 16 + lr;
            short8 af = *(const short8*)(ldsR + row * 128 + ((kc * 64 + lq * 16) ^ ((lr & 7) << 4)));
            racc[mf][0] = __builtin_amdgcn_mfma_f32_16x16x32_bf16(af, ob2[0], racc[mf][0], 0, 0, 0);
            racc[mf][1] = __builtin_amdgcn_mfma_f32_16x16x32_bf16(af, ob2[1], racc[mf][1], 0, 0, 0);
        }
    }

    // epilogue: h_out = h_in + res/sqrt(2) (bf16), skips += skip (f32)
    const float inv_s2 = 0.70710678118654752f;
    #pragma unroll
    for (int nf = 0; nf < 2; ++nf) {
        int t = t0 + nf * 16 + lr;
        size_t base = ((size_t)b * Tx + t) * 64;
        #pragma unroll
        for (int mf = 0; mf < 4; ++mf) {
            unsigned short* hp = (unsigned short*)&hold[nf][mf];
            unsigned short hnew[4];
            #pragma unroll
            for (int r = 0; r < 4; ++r)
                hnew[r] = f2bf(bf2f(hp[r]) + racc[mf][nf][r] * inv_s2);
            u32x2 hw;
            hw[0] = (unsigned int)hnew[0] | ((unsigned int)hnew[1] << 16);
            hw[1] = (unsigned int)hnew[2] | ((unsigned int)hnew[3] << 16);
            *(u32x2*)(h_out + base + mf * 16 + lq * 4) = hw;
            f32x4 sk = skold[nf][mf] + racc[mf + 4][nf];
            *(f32x4*)(skips + base + mf * 16 + lq * 4) = sk;
        }
    }
}

// ---------------- final: relu(skip_conv(skips*isc)) -> out_conv, MFMA ----------------
__launch_bounds__(256, 2)
__global__ void out_kernel(const float* __restrict__ skips,
                           const unsigned short* __restrict__ skw,   // [64][64] bf16
                           const float* __restrict__ skb,
                           const unsigned short* __restrict__ oww,   // [80][64] bf16
                           const float* __restrict__ obias,
                           float* __restrict__ y) {
    __shared__ __align__(16) unsigned char ldsY[16384];
    int tid = threadIdx.x;
    int wid = tid >> 6;
    int lane = tid & 63;
    int lr = lane & 15;
    int lq = lane >> 4;

    int bid = blockIdx.x;
    int wg = (bid & 7) * 64 + (bid >> 3);
    int P0 = wg * 128 + wid * 32;
    int b = P0 >> 13;
    int t0 = P0 & 8191;

    short8 A1[4][2];
    #pragma unroll
    for (int mf = 0; mf < 4; ++mf)
        #pragma unroll
        for (int kc = 0; kc < 2; ++kc)
            A1[mf][kc] = *(const short8*)(skw + (mf * 16 + lr) * 64 + kc * 32 + lq * 8);

    short8 Bs[2][2];
    #pragma unroll
    for (int nf = 0; nf < 2; ++nf) {
        const float* sp = skips + ((size_t)P0 + nf * 16 + lr) * 64;
        #pragma unroll
        for (int kc = 0; kc < 2; ++kc) {
            f32x4 u = *(const f32x4*)(sp + kc * 32 + lq * 8);
            f32x4 v = *(const f32x4*)(sp + kc * 32 + lq * 8 + 4);
            short8 z;
            #pragma unroll
            for (int r = 0; r < 4; ++r) {
                z[r] = (short)f2bf(u[r]);
                z[r + 4] = (short)f2bf(v[r]);
            }
            Bs[nf][kc] = z;
        }
    }

    f32x4 acc1[4][2];
    #pragma unroll
    for (int mf = 0; mf < 4; ++mf) {
        f32x4 bb = *(const f32x4*)(skb + mf * 16 + lq * 4);
        acc1[mf][0] = bb;
        acc1[mf][1] = bb;
    }
    #pragma unroll
    for (int kc = 0; kc < 2; ++kc)
        #pragma unroll
        for (int mf = 0; mf < 4; ++mf) {
            acc1[mf][0] = __builtin_amdgcn_mfma_f32_16x16x32_bf16(A1[mf][kc], Bs[0][kc], acc1[mf][0], 0, 0, 0);
            acc1[mf][1] = __builtin_amdgcn_mfma_f32_16x16x32_bf16(A1[mf][kc], Bs[1][kc], acc1[mf][1], 0, 0, 0);
        }

    unsigned char* myY = ldsY + wid * 4096;
    #pragma unroll
    for (int mf = 0; mf < 4; ++mf)
        #pragma unroll
        for (int nf = 0; nf < 2; ++nf) {
            int p = nf * 16 + lr;
            unsigned short ob[4];
            #pragma unroll
            for (int r = 0; r < 4; ++r)
                ob[r] = f2bf(fmaxf(acc1[mf][nf][r], 0.f));
            u32x2 pk;
            pk[0] = (unsigned int)ob[0] | ((unsigned int)ob[1] << 16);
            pk[1] = (unsigned int)ob[2] | ((unsigned int)ob[3] << 16);
            *(u32x2*)(myY + p * 128 + ((mf * 32 + lq * 8) ^ ((p & 7) << 4))) = pk;
        }

    short8 B2[2][2];
    #pragma unroll
    for (int nf = 0; nf < 2; ++nf) {
        int p = nf * 16 + lr;
        #pragma unroll
        for (int kc = 0; kc < 2; ++kc)
            B2[nf][kc] = *(const short8*)(myY + p * 128 + ((kc * 64 + lq * 16) ^ ((p & 7) << 4)));
    }
    f32x4 acc2[5][2];
    #pragma unroll
    for (int mf = 0; mf < 5; ++mf) {
        f32x4 bb = *(const f32x4*)(obias + mf * 16 + lq * 4);
        acc2[mf][0] = bb;
        acc2[mf][1] = bb;
    }
    #pragma unroll
    for (int kc = 0; kc < 2; ++kc)
        #pragma unroll
        for (int mf = 0; mf < 5; ++mf) {
            short8 A2 = *(const short8*)(oww + (mf * 16 + lr) * 64 + kc * 32 + lq * 8);
            acc2[mf][0] = __builtin_amdgcn_mfma_f32_16x16x32_bf16(A2, B2[0][kc], acc2[mf][0], 0, 0, 0);
            acc2[mf][1] = __builtin_amdgcn_mfma_f32_16x16x32_bf16(A2, B2[1][kc], acc2[mf][1], 0, 0, 0);
        }

    #pragma unroll
    for (int mf = 0; mf < 5; ++mf)
        #pragma unroll
        for (int nf = 0; nf < 2; ++nf) {
            int t = t0 + nf * 16 + lr;
            #pragma unroll
            for (int r = 0; r < 4; ++r) {
                int m = mf * 16 + lq * 4 + r;
                y[((size_t)b * NM + m) * Tx + t] = acc2[mf][nf][r];
            }
        }
}

extern "C" void kernel_launch(void* const* d_in, const int* in_sizes, int n_in,
                              void* d_out, int out_size, void* d_ws, size_t ws_size,
                              hipStream_t stream) {
    const float* x       = (const float*)d_in[0];
    const int*   tin     = (const int*)d_in[1];
    const float* c_emb   = (const float*)d_in[2];
    const float* in_w    = (const float*)d_in[3];
    const float* in_b    = (const float*)d_in[4];
    const float* te_w1   = (const float*)d_in[5];
    const float* te_b1   = (const float*)d_in[6];
    const float* te_w2   = (const float*)d_in[7];
    const float* te_b2   = (const float*)d_in[8];
    const float* dconv_w = (const float*)d_in[9];
    const float* dconv_b = (const float*)d_in[10];
    const float* tproj_w = (const float*)d_in[11];
    const float* tproj_b = (const float*)d_in[12];
    const float* cproj_w = (const float*)d_in[13];
    const float* cproj_b = (const float*)d_in[14];
    const float* rs_w    = (const float*)d_in[15];
    const float* rs_b    = (const float*)d_in[16];
    const float* skip_w  = (const float*)d_in[17];
    const float* skip_b  = (const float*)d_in[18];
    const float* out_w   = (const float*)d_in[19];
    const float* out_b   = (const float*)d_in[20];

    char* ws = (char*)d_ws;
    float* te_buf         = (float*)(ws + 0);                 // 4KB
    float* gbias          = (float*)(ws + 4096);              // 120KB -> 126976
    unsigned short* skw16 = (unsigned short*)(ws + 126976);   // 8KB  -> 135168
    unsigned short* oww16 = (unsigned short*)(ws + 135168);   // 10KB -> 145408
    unsigned short* wc2   = (unsigned short*)(ws + 145408);   // 1.40625MB -> 1619968
    unsigned short* wr2   = (unsigned short*)(ws + 1619968);  // 480KB -> 2111488
    unsigned short* h0    = (unsigned short*)(ws + 2111488);  // 8MB -> 10500096
    unsigned short* h1    = (unsigned short*)(ws + 10500096); // 8MB -> 18888704
    float* skips          = (float*)(ws + 18888704);          // 16MB -> 35665920

    te_kernel<<<8, 512, 0, stream>>>(tin, te_w1, te_b1, te_w2, te_b2, te_buf);
    gbias_kernel<<<240, 128, 0, stream>>>(te_buf, c_emb, tproj_w, tproj_b,
                                          cproj_w, cproj_b, dconv_b, gbias);
    prep_kernel<<<3876, 256, 0, stream>>>(dconv_w, rs_w, skip_w, out_w,
                                          wc2, wr2, skw16, oww16);
    in_conv_kernel<<<dim3(64, 8), 256, 0, stream>>>(x, in_w, in_b, h0);

    unsigned short* hin = h0;
    unsigned short* hout = h1;
    for (int i = 0; i < NL; ++i) {
        int dil = 1 << (i % 10);
        layer_kernel<<<256, 512, 0, stream>>>(hin, hout, skips,
                                              wc2 + (size_t)i * 24576,
                                              wr2 + (size_t)i * 8192,
                                              gbias + (size_t)i * 1024,
                                              rs_b + (size_t)i * 128,
                                              dil, i == 0 ? 1 : 0);
        unsigned short* tmp = hin; hin = hout; hout = tmp;
    }
    out_kernel<<<512, 256, 0, stream>>>(skips, skw16, skip_b, oww16, out_b,
                                        (float*)d_out);
}

// Round 5
// 558.777 us; speedup vs baseline: 5.3124x; 1.0560x over previous
//
#include <hip/hip_runtime.h>
#include <hip/hip_bf16.h>
#include <math.h>

#define NL 30
#define NM 80
#define Bx 8
#define Tx 8192

typedef short short8 __attribute__((ext_vector_type(8)));
typedef float f32x4 __attribute__((ext_vector_type(4)));
typedef unsigned int u32x2 __attribute__((ext_vector_type(2)));
typedef unsigned int u32x4 __attribute__((ext_vector_type(4)));

__device__ __forceinline__ float bf2f(unsigned short u) {
    union { unsigned int u; float f; } v; v.u = ((unsigned int)u) << 16; return v.f;
}
__device__ __forceinline__ unsigned short f2bf(float f) {
    union { float f; unsigned int u; } v; v.f = f;
    unsigned int r = v.u + 0x7FFFu + ((v.u >> 16) & 1u);
    return (unsigned short)(r >> 16);
}

#if defined(__has_builtin)
#if __has_builtin(__builtin_amdgcn_global_load_lds)
#define HAS_GLL 1
#endif
#endif

__device__ __forceinline__ void gll16(const void* g, void* l) {
#ifdef HAS_GLL
    __builtin_amdgcn_global_load_lds(
        (const __attribute__((address_space(1))) void*)g,
        (__attribute__((address_space(3))) void*)l, 16, 0, 0);
#else
    int lane = threadIdx.x & 63;
    *(u32x4*)((char*)l + lane * 16) = *(const u32x4*)((const char*)g + lane * 16);
#endif
}

// ---------------- time-embedding MLP: 8 blocks (one per batch) ----------------
__global__ void te_kernel(const int* __restrict__ tin,
                          const float* __restrict__ w1, const float* __restrict__ b1,
                          const float* __restrict__ w2, const float* __restrict__ b2,
                          float* __restrict__ te_out) {
    __shared__ float emb[128];
    __shared__ float h1s[512];
    __shared__ float red[512];
    int b = blockIdx.x, tid = threadIdx.x;
    if (tid < 64) {
        float fr = expf(-(float)tid * (logf(10000.f) / 63.f));
        float ang = (float)tin[b] * fr;
        emb[tid] = sinf(ang);
        emb[tid + 64] = cosf(ang);
    }
    __syncthreads();
    float a = b1[tid];
    const float* wr = w1 + tid * 128;
    for (int k = 0; k < 128; ++k) a = fmaf(emb[k], wr[k], a);
    float sp = (a > 15.f) ? a : log1pf(expf(a));
    h1s[tid] = a * tanhf(sp);
    __syncthreads();
    int o = tid & 127, q = tid >> 7;
    float p = 0.f;
    const float* wr2 = w2 + o * 512 + q * 128;
    const float* hq = h1s + q * 128;
    for (int k = 0; k < 128; ++k) p = fmaf(hq[k], wr2[k], p);
    red[tid] = p;
    __syncthreads();
    if (q == 0)
        te_out[b * 128 + o] = b2[o] + red[o] + red[o + 128] + red[o + 256] + red[o + 384];
}

// ---------------- per-layer (b,ch) bias: coalesced wave-reduce version ----------------
// block = (l,b) pair, 512 thr = 8 waves; wave handles ch = wid + 8*i, i = 0..15.
// All global reads coalesced across 64 lanes; 64-lane shfl_xor reduction.
__global__ void gbias_kernel(const float* __restrict__ te,
                             const float* __restrict__ cemb,
                             const float* __restrict__ tpw, const float* __restrict__ tpb,
                             const float* __restrict__ cpw, const float* __restrict__ cpb,
                             const float* __restrict__ dcb,
                             float* __restrict__ gbias) {
    int l = blockIdx.x >> 3;
    int b = blockIdx.x & 7;
    int tid = threadIdx.x, wid = tid >> 6, lane = tid & 63;
    float te0 = te[b * 128 + lane];
    float te1 = te[b * 128 + 64 + lane];
    float ce0 = cemb[b * 256 + lane];
    float ce1 = cemb[b * 256 + 64 + lane];
    float ce2 = cemb[b * 256 + 128 + lane];
    float ce3 = cemb[b * 256 + 192 + lane];
    #pragma unroll 4
    for (int i = 0; i < 16; ++i) {
        int ch = i * 8 + wid;
        const float* wr = tpw + (size_t)(l * 128 + ch) * 128;
        float s = te0 * wr[lane] + te1 * wr[lane + 64];
        const float* wc = cpw + (size_t)(l * 128 + ch) * 256;
        float sc = ce0 * wc[lane] + ce1 * wc[lane + 64] + ce2 * wc[lane + 128] + ce3 * wc[lane + 192];
        #pragma unroll
        for (int off = 32; off >= 1; off >>= 1) {
            s += __shfl_xor(s, off, 64);
            sc += __shfl_xor(sc, off, 64);
        }
        if (lane == 0) {
            float tp = tpb[l * 128 + ch] + s;
            float cp = cpb[l * 128 + ch] + sc;
            float s1 = tp / fmaxf(fabsf(tp), 1e-12f);
            float s2 = cp / fmaxf(fabsf(cp), 1e-12f);
            gbias[(l * 8 + b) * 128 + ch] = dcb[l * 128 + ch] + s1 + s2;
        }
    }
}

// ---------------- weight prep ----------------
// wc2 AND wr2 stored PRE-SWIZZLED so a linear gll16 copy lands in the XOR-swizzled
// LDS layout: linear chunk c -> row=c>>3, phys slot p=c&7 holds col16 = p ^ (row&7).
__global__ void prep_kernel(const float* __restrict__ dconv_w, const float* __restrict__ rs_w,
                            const float* __restrict__ skip_w, const float* __restrict__ out_w,
                            unsigned short* __restrict__ wc2, unsigned short* __restrict__ wr2,
                            unsigned short* __restrict__ skw16, unsigned short* __restrict__ oww16) {
    int idx = blockIdx.x * 256 + threadIdx.x;
    const int totC = NL * 24576;           // 737280
    const int totR = NL * 128 * 64;        // 245760
    if (idx < totC) {
        int l = idx / 24576;
        int r = idx - l * 24576;
        int c = r >> 3;
        int e = r & 7;
        int row = c >> 3;
        int p = c & 7;
        int col16 = p ^ (row & 7);
        int ic = col16 * 8 + e;
        int tap = row >> 7;
        int oc = row & 127;
        wc2[idx] = f2bf(dconv_w[((size_t)(l * 128 + oc) * 64 + ic) * 3 + tap]);
    } else if (idx < totC + totR) {
        int j = idx - totC;
        int l = j / 8192;
        int r = j - l * 8192;
        int c = r >> 3;
        int e = r & 7;
        int row = c >> 3;
        int p = c & 7;
        int col16 = p ^ (row & 7);
        int ic = col16 * 8 + e;
        wr2[j] = f2bf(rs_w[(size_t)(l * 128 + row) * 64 + ic]);
    } else if (idx < totC + totR + 4096) {
        int j = idx - totC - totR;
        skw16[j] = f2bf(skip_w[j] * 0.18257418583505536f);
    } else if (idx < totC + totR + 4096 + 5120) {
        int j = idx - totC - totR - 4096;
        oww16[j] = f2bf(out_w[j]);
    }
}

// ---------------- input conv 80->64 + transpose to (B,T,64) bf16 ----------------
__global__ void in_conv_kernel(const float* __restrict__ x, const float* __restrict__ w,
                               const float* __restrict__ bias, unsigned short* __restrict__ h0) {
    __shared__ float wT[NM][64];
    int tid = threadIdx.x;
    for (int i = tid; i < NM * 64; i += 256) {
        int m = i >> 6, c = i & 63;
        wT[m][c] = w[c * NM + m];
    }
    __syncthreads();
    int b = blockIdx.y;
    int t = blockIdx.x * 128 + (tid >> 1);
    int ch0 = (tid & 1) * 32;
    const float* xp = x + (size_t)b * NM * Tx + t;
    float acc[32];
    #pragma unroll
    for (int c = 0; c < 32; ++c) acc[c] = bias[ch0 + c];
    for (int m = 0; m < NM; ++m) {
        float xv = xp[(size_t)m * Tx];
        #pragma unroll
        for (int c = 0; c < 32; ++c) acc[c] = fmaf(xv, wT[m][ch0 + c], acc[c]);
    }
    unsigned short* hp = h0 + ((size_t)b * Tx + t) * 64 + ch0;
    #pragma unroll
    for (int c = 0; c < 32; c += 2) {
        unsigned int p = (unsigned int)f2bf(acc[c]) | ((unsigned int)f2bf(acc[c + 1]) << 16);
        *(unsigned int*)(hp + c) = p;
    }
}

// ---------------- fused residual layer: 2 blocks/CU occupancy version ----------------
// 8 waves; wave = M128 out-ch x N16 positions (block = 128 positions).
// Grid 512 = 2 blocks/CU (LDS 80KB x2 = 160KB, 4 waves/SIMD).
// Wave-private out-exchange (no conv->rs barrier); same swizzles as r4.
__launch_bounds__(512, 4)
__global__ void layer_kernel(const unsigned short* __restrict__ h_in,
                             unsigned short* __restrict__ h_out,
                             float* __restrict__ skips,
                             const unsigned short* __restrict__ wc2,  // pre-swizzled
                             const unsigned short* __restrict__ wr2,  // pre-swizzled
                             const float* __restrict__ gbias,         // [8][128]
                             const float* __restrict__ rsb,           // [128]
                             int dil, int first) {
    __shared__ __align__(16) unsigned char lds[81920];
    unsigned char* ldsA = lds;            // 48KB conv weights
    unsigned char* ldsR = lds + 49152;    // 16KB rs weights
    unsigned char* ldsO = lds + 65536;    // 16KB out exchange (2KB/wave)

    int tid = threadIdx.x;
    int wid = tid >> 6, lane = tid & 63, lr = lane & 15, lq = lane >> 4;

    // stage weights: linear gll16 copies (content pre-swizzled)
    #pragma unroll
    for (int j = 0; j < 6; ++j) {
        int cbase = j * 512 + wid * 64;
        gll16(wc2 + (size_t)(cbase + lane) * 8, ldsA + cbase * 16);
    }
    #pragma unroll
    for (int j = 0; j < 2; ++j) {
        int cbase = j * 512 + wid * 64;
        gll16(wr2 + (size_t)(cbase + lane) * 8, ldsR + cbase * 16);
    }

    int bid = blockIdx.x;
    int wg = (bid & 7) * 64 + (bid >> 3);   // batch k -> XCD k
    int b = wg >> 6;
    int t0 = ((wg & 63) << 7) + wid * 16;

    // prefetch conv B-fragments (overlaps weight staging)
    const unsigned short* hb = h_in + (size_t)b * Tx * 64;
    short8 bv[3][2];
    #pragma unroll
    for (int tap = 0; tap < 3; ++tap) {
        int toff = (tap - 1) * dil;
        int t = t0 + lr + toff;
        bool v = ((unsigned)t < (unsigned)Tx);
        #pragma unroll
        for (int kc = 0; kc < 2; ++kc) {
            short8 z = {0, 0, 0, 0, 0, 0, 0, 0};
            if (v) z = *(const short8*)(hb + t * 64 + kc * 32 + lq * 8);
            bv[tap][kc] = z;
        }
    }

    // conv accumulators init with per-(b,ch) bias
    f32x4 acc[8];
    #pragma unroll
    for (int mf = 0; mf < 8; ++mf)
        acc[mf] = *(const f32x4*)(gbias + b * 128 + mf * 16 + lq * 4);
    __syncthreads();   // weights staged

    #pragma unroll
    for (int tap = 0; tap < 3; ++tap) {
        #pragma unroll
        for (int kc = 0; kc < 2; ++kc) {
            #pragma unroll
            for (int mf = 0; mf < 8; ++mf) {
                int row = tap * 128 + mf * 16 + lr;
                short8 af = *(const short8*)(ldsA + row * 128 + ((kc * 64 + lq * 16) ^ ((lr & 7) << 4)));
                acc[mf] = __builtin_amdgcn_mfma_f32_16x16x32_bf16(af, bv[tap][kc], acc[mf], 0, 0, 0);
            }
        }
    }

    // gating -> wave-private ldsO tile (16 pos x 64 ch)
    unsigned char* myO = ldsO + wid * 2048;
    #pragma unroll
    for (int mf = 0; mf < 4; ++mf) {
        int p = lr;
        unsigned short ob[4];
        #pragma unroll
        for (int r = 0; r < 4; ++r) {
            float g = acc[mf][r];       // gate: ch 0..63
            float f = acc[mf + 4][r];   // filt: ch 64..127
            f = fminf(f, 15.f);
            g = fminf(g, 30.f);
            float ea = __builtin_amdgcn_exp2f(f * 2.8853900817779268f);
            float eb = __builtin_amdgcn_exp2f(g * 1.4426950408889634f);
            float num = (ea - 1.f) * eb;
            float den = (ea + 1.f) * (1.f + eb);
            ob[r] = f2bf(num * __builtin_amdgcn_rcpf(den));
        }
        u32x2 pk;
        pk[0] = (unsigned int)ob[0] | ((unsigned int)ob[1] << 16);
        pk[1] = (unsigned int)ob[2] | ((unsigned int)ob[3] << 16);
        *(u32x2*)(myO + p * 128 + ((mf * 32 + lq * 8) ^ ((p & 7) << 4))) = pk;
    }

    // prefetch epilogue operands (independent of rs MFMAs)
    int te_ = t0 + lr;
    size_t base = ((size_t)b * Tx + te_) * 64;
    u32x2 hold[4];
    f32x4 skold[4];
    #pragma unroll
    for (int mf = 0; mf < 4; ++mf) {
        hold[mf] = *(const u32x2*)(h_in + base + mf * 16 + lq * 4);
        if (!first) skold[mf] = *(const f32x4*)(skips + base + mf * 16 + lq * 4);
        else { skold[mf][0] = 0.f; skold[mf][1] = 0.f; skold[mf][2] = 0.f; skold[mf][3] = 0.f; }
    }

    // rs 1x1 conv: 64 -> 128
    f32x4 racc[8];
    #pragma unroll
    for (int mf = 0; mf < 8; ++mf)
        racc[mf] = *(const f32x4*)(rsb + mf * 16 + lq * 4);
    #pragma unroll
    for (int kc = 0; kc < 2; ++kc) {
        int p = lr;
        short8 ov = *(const short8*)(myO + p * 128 + ((kc * 64 + lq * 16) ^ ((p & 7) << 4)));
        #pragma unroll
        for (int mf = 0; mf < 8; ++mf) {
            int row = mf * 16 + lr;
            short8 af = *(const short8*)(ldsR + row * 128 + ((kc * 64 + lq * 16) ^ ((lr & 7) << 4)));
            racc[mf] = __builtin_amdgcn_mfma_f32_16x16x32_bf16(af, ov, racc[mf], 0, 0, 0);
        }
    }

    // epilogue: h_out = h_in + res/sqrt(2) (bf16), skips += skip (f32)
    const float inv_s2 = 0.70710678118654752f;
    #pragma unroll
    for (int mf = 0; mf < 4; ++mf) {
        unsigned short* hp = (unsigned short*)&hold[mf];
        unsigned short hnew[4];
        #pragma unroll
        for (int r = 0; r < 4; ++r)
            hnew[r] = f2bf(bf2f(hp[r]) + racc[mf][r] * inv_s2);
        u32x2 hw;
        hw[0] = (unsigned int)hnew[0] | ((unsigned int)hnew[1] << 16);
        hw[1] = (unsigned int)hnew[2] | ((unsigned int)hnew[3] << 16);
        *(u32x2*)(h_out + base + mf * 16 + lq * 4) = hw;
        f32x4 sk = skold[mf] + racc[mf + 4];
        *(f32x4*)(skips + base + mf * 16 + lq * 4) = sk;
    }
}

// ---------------- final: relu(skip_conv(skips*isc)) -> out_conv, MFMA ----------------
__launch_bounds__(256, 2)
__global__ void out_kernel(const float* __restrict__ skips,
                           const unsigned short* __restrict__ skw,   // [64][64] bf16
                           const float* __restrict__ skb,
                           const unsigned short* __restrict__ oww,   // [80][64] bf16
                           const float* __restrict__ obias,
                           float* __restrict__ y) {
    __shared__ __align__(16) unsigned char ldsY[16384];
    int tid = threadIdx.x;
    int wid = tid >> 6;
    int lane = tid & 63;
    int lr = lane & 15;
    int lq = lane >> 4;

    int bid = blockIdx.x;
    int wg = (bid & 7) * 64 + (bid >> 3);
    int P0 = wg * 128 + wid * 32;
    int b = P0 >> 13;
    int t0 = P0 & 8191;

    short8 A1[4][2];
    #pragma unroll
    for (int mf = 0; mf < 4; ++mf)
        #pragma unroll
        for (int kc = 0; kc < 2; ++kc)
            A1[mf][kc] = *(const short8*)(skw + (mf * 16 + lr) * 64 + kc * 32 + lq * 8);

    short8 Bs[2][2];
    #pragma unroll
    for (int nf = 0; nf < 2; ++nf) {
        const float* sp = skips + ((size_t)P0 + nf * 16 + lr) * 64;
        #pragma unroll
        for (int kc = 0; kc < 2; ++kc) {
            f32x4 u = *(const f32x4*)(sp + kc * 32 + lq * 8);
            f32x4 v = *(const f32x4*)(sp + kc * 32 + lq * 8 + 4);
            short8 z;
            #pragma unroll
            for (int r = 0; r < 4; ++r) {
                z[r] = (short)f2bf(u[r]);
                z[r + 4] = (short)f2bf(v[r]);
            }
            Bs[nf][kc] = z;
        }
    }

    f32x4 acc1[4][2];
    #pragma unroll
    for (int mf = 0; mf < 4; ++mf) {
        f32x4 bb = *(const f32x4*)(skb + mf * 16 + lq * 4);
        acc1[mf][0] = bb;
        acc1[mf][1] = bb;
    }
    #pragma unroll
    for (int kc = 0; kc < 2; ++kc)
        #pragma unroll
        for (int mf = 0; mf < 4; ++mf) {
            acc1[mf][0] = __builtin_amdgcn_mfma_f32_16x16x32_bf16(A1[mf][kc], Bs[0][kc], acc1[mf][0], 0, 0, 0);
            acc1[mf][1] = __builtin_amdgcn_mfma_f32_16x16x32_bf16(A1[mf][kc], Bs[1][kc], acc1[mf][1], 0, 0, 0);
        }

    unsigned char* myY = ldsY + wid * 4096;
    #pragma unroll
    for (int mf = 0; mf < 4; ++mf)
        #pragma unroll
        for (int nf = 0; nf < 2; ++nf) {
            int p = nf * 16 + lr;
            unsigned short ob[4];
            #pragma unroll
            for (int r = 0; r < 4; ++r)
                ob[r] = f2bf(fmaxf(acc1[mf][nf][r], 0.f));
            u32x2 pk;
            pk[0] = (unsigned int)ob[0] | ((unsigned int)ob[1] << 16);
            pk[1] = (unsigned int)ob[2] | ((unsigned int)ob[3] << 16);
            *(u32x2*)(myY + p * 128 + ((mf * 32 + lq * 8) ^ ((p & 7) << 4))) = pk;
        }

    short8 B2[2][2];
    #pragma unroll
    for (int nf = 0; nf < 2; ++nf) {
        int p = nf * 16 + lr;
        #pragma unroll
        for (int kc = 0; kc < 2; ++kc)
            B2[nf][kc] = *(const short8*)(myY + p * 128 + ((kc * 64 + lq * 16) ^ ((p & 7) << 4)));
    }
    f32x4 acc2[5][2];
    #pragma unroll
    for (int mf = 0; mf < 5; ++mf) {
        f32x4 bb = *(const f32x4*)(obias + mf * 16 + lq * 4);
        acc2[mf][0] = bb;
        acc2[mf][1] = bb;
    }
    #pragma unroll
    for (int kc = 0; kc < 2; ++kc)
        #pragma unroll
        for (int mf = 0; mf < 5; ++mf) {
            short8 A2 = *(const short8*)(oww + (mf * 16 + lr) * 64 + kc * 32 + lq * 8);
            acc2[mf][0] = __builtin_amdgcn_mfma_f32_16x16x32_bf16(A2, B2[0][kc], acc2[mf][0], 0, 0, 0);
            acc2[mf][1] = __builtin_amdgcn_mfma_f32_16x16x32_bf16(A2, B2[1][kc], acc2[mf][1], 0, 0, 0);
        }

    #pragma unroll
    for (int mf = 0; mf < 5; ++mf)
        #pragma unroll
        for (int nf = 0; nf < 2; ++nf) {
            int t = t0 + nf * 16 + lr;
            #pragma unroll
            for (int r = 0; r < 4; ++r) {
                int m = mf * 16 + lq * 4 + r;
                y[((size_t)b * NM + m) * Tx + t] = acc2[mf][nf][r];
            }
        }
}

extern "C" void kernel_launch(void* const* d_in, const int* in_sizes, int n_in,
                              void* d_out, int out_size, void* d_ws, size_t ws_size,
                              hipStream_t stream) {
    const float* x       = (const float*)d_in[0];
    const int*   tin     = (const int*)d_in[1];
    const float* c_emb   = (const float*)d_in[2];
    const float* in_w    = (const float*)d_in[3];
    const float* in_b    = (const float*)d_in[4];
    const float* te_w1   = (const float*)d_in[5];
    const float* te_b1   = (const float*)d_in[6];
    const float* te_w2   = (const float*)d_in[7];
    const float* te_b2   = (const float*)d_in[8];
    const float* dconv_w = (const float*)d_in[9];
    const float* dconv_b = (const float*)d_in[10];
    const float* tproj_w = (const float*)d_in[11];
    const float* tproj_b = (const float*)d_in[12];
    const float* cproj_w = (const float*)d_in[13];
    const float* cproj_b = (const float*)d_in[14];
    const float* rs_w    = (const float*)d_in[15];
    const float* rs_b    = (const float*)d_in[16];
    const float* skip_w  = (const float*)d_in[17];
    const float* skip_b  = (const float*)d_in[18];
    const float* out_w   = (const float*)d_in[19];
    const float* out_b   = (const float*)d_in[20];

    char* ws = (char*)d_ws;
    float* te_buf         = (float*)(ws + 0);                 // 4KB
    float* gbias          = (float*)(ws + 4096);              // 120KB -> 126976
    unsigned short* skw16 = (unsigned short*)(ws + 126976);   // 8KB  -> 135168
    unsigned short* oww16 = (unsigned short*)(ws + 135168);   // 10KB -> 145408
    unsigned short* wc2   = (unsigned short*)(ws + 145408);   // 1.40625MB -> 1619968
    unsigned short* wr2   = (unsigned short*)(ws + 1619968);  // 480KB -> 2111488
    unsigned short* h0    = (unsigned short*)(ws + 2111488);  // 8MB -> 10500096
    unsigned short* h1    = (unsigned short*)(ws + 10500096); // 8MB -> 18888704
    float* skips          = (float*)(ws + 18888704);          // 16MB -> 35665920

    te_kernel<<<8, 512, 0, stream>>>(tin, te_w1, te_b1, te_w2, te_b2, te_buf);
    gbias_kernel<<<240, 512, 0, stream>>>(te_buf, c_emb, tproj_w, tproj_b,
                                          cproj_w, cproj_b, dconv_b, gbias);
    prep_kernel<<<3876, 256, 0, stream>>>(dconv_w, rs_w, skip_w, out_w,
                                          wc2, wr2, skw16, oww16);
    in_conv_kernel<<<dim3(64, 8), 256, 0, stream>>>(x, in_w, in_b, h0);

    unsigned short* hin = h0;
    unsigned short* hout = h1;
    for (int i = 0; i < NL; ++i) {
        int dil = 1 << (i % 10);
        layer_kernel<<<512, 512, 0, stream>>>(hin, hout, skips,
                                              wc2 + (size_t)i * 24576,
                                              wr2 + (size_t)i * 8192,
                                              gbias + (size_t)i * 1024,
                                              rs_b + (size_t)i * 128,
                                              dil, i == 0 ? 1 : 0);
        unsigned short* tmp = hin; hin = hout; hout = tmp;
    }
    out_kernel<<<512, 256, 0, stream>>>(skips, skw16, skip_b, oww16, out_b,
                                        (float*)d_out);
}